// Round 3
// baseline (949.641 us; speedup 1.0000x reference)
//
#include <hip/hip_runtime.h>
#include <math.h>

#define HH_ 96
#define WW_ 160
#define HW 15360          // 96*160
#define NPIX 61440        // 4*HW
#define CC 256
#define C0 320            // padded conv0 Cin
#define FF 64
#define H2 192
#define W2 320
#define OHW 61440         // 192*320
#define HO 768
#define WO 1280

typedef __attribute__((ext_vector_type(8))) short short8;
typedef __attribute__((ext_vector_type(4))) float f32x4;

__device__ __forceinline__ float bf2f(ushort u) {
    union { unsigned int i; float f; } v; v.i = ((unsigned int)u) << 16; return v.f;
}
__device__ __forceinline__ ushort f2bf(float f) {
    union { float f; unsigned int i; } v; v.f = f;
    unsigned int u = v.i;
    return (ushort)((u + 0x7FFFu + ((u >> 16) & 1u)) >> 16);
}
__device__ __forceinline__ float bfbits_lo(unsigned int u) {   // low ushort -> float
    union { unsigned int i; float f; } v; v.i = u << 16; return v.f;
}
__device__ __forceinline__ float bfbits_hi(unsigned int u) {   // high ushort -> float
    union { unsigned int i; float f; } v; v.i = u & 0xFFFF0000u; return v.f;
}

// ------------------------------------------------------------------ stats ---
// 4 threads per pixel (64 channels each) -> 3.75 waves/SIMD
__global__ void stats_kernel(const float* __restrict__ x1, const float* __restrict__ x2,
                             const float* __restrict__ xt,
                             float* __restrict__ inv1, float* __restrict__ inv2,
                             float* __restrict__ meanb, float* __restrict__ rstdb) {
    int tid = blockIdx.x * blockDim.x + threadIdx.x;
    int p = tid >> 2, q = tid & 3;
    if (p >= NPIX) return;
    int b = p / HW, rem = p % HW;
    size_t base = (size_t)b * CC * HW + rem;
    float s1 = 0.f, s2 = 0.f, sm = 0.f, sq = 0.f;
    for (int i = 0; i < 64; ++i) {
        int c = q * 64 + i;
        size_t a = base + (size_t)c * HW;
        float v1 = x1[a], v2 = x2[a], v3 = xt[a];
        s1 += v1 * v1; s2 += v2 * v2; sm += v3; sq += v3 * v3;
    }
    s1 += __shfl_xor(s1, 1); s1 += __shfl_xor(s1, 2);
    s2 += __shfl_xor(s2, 1); s2 += __shfl_xor(s2, 2);
    sm += __shfl_xor(sm, 1); sm += __shfl_xor(sm, 2);
    sq += __shfl_xor(sq, 1); sq += __shfl_xor(sq, 2);
    if (q == 0) {
        inv1[p] = 1.f / fmaxf(sqrtf(s1), 1e-12f);
        inv2[p] = 1.f / fmaxf(sqrtf(s2), 1e-12f);
        float m = sm / CC;
        float var = fmaxf(sq / CC - m * m, 0.f);
        meanb[p] = m; rstdb[p] = rsqrtf(var + 1e-5f);
    }
}

// ------------------------------- NCHW f32 -> NHWC bf16, fused L2 normalize --
__global__ void pack_x_kernel(const float* __restrict__ in, const float* __restrict__ inv,
                              ushort* __restrict__ out) {
    __shared__ float tile[64][68];
    int t = threadIdx.x;
    int pxt = blockIdx.x, ct = blockIdx.y, b = blockIdx.z;
    const float* src = in + ((size_t)b * CC + ct * 64) * HW + pxt * 64;
    for (int i = 0; i < 16; ++i) {
        int c_l = i * 4 + (t >> 6);
        int px_l = t & 63;
        tile[px_l][c_l] = src[(size_t)c_l * HW + px_l];
    }
    __syncthreads();
    int px_l = t >> 2, cg = t & 3;
    int p = b * HW + pxt * 64 + px_l;
    float s = inv[p];
    size_t ob = (size_t)p * CC + ct * 64 + cg * 16;
    short8 v0, v1;
    for (int j = 0; j < 8; ++j) {
        v0[j] = (short)f2bf(tile[px_l][cg * 16 + j] * s);
        v1[j] = (short)f2bf(tile[px_l][cg * 16 + 8 + j] * s);
    }
    *(short8*)(out + ob) = v0;
    *(short8*)(out + ob + 8) = v1;
}

// ------------------------------------------- LN + pack into X0 (hi/lo bf16) -
__global__ void pack_ln_kernel(const float* __restrict__ xt,
                               const float* __restrict__ gam, const float* __restrict__ bet,
                               const float* __restrict__ meanb, const float* __restrict__ rstdb,
                               ushort* __restrict__ Xhi, ushort* __restrict__ Xlo) {
    __shared__ float tile[64][68];
    int t = threadIdx.x;
    int pxt = blockIdx.x, ct = blockIdx.y, b = blockIdx.z;
    const float* src = xt + ((size_t)b * CC + ct * 64) * HW + pxt * 64;
    for (int i = 0; i < 16; ++i) {
        int c_l = i * 4 + (t >> 6);
        int px_l = t & 63;
        tile[px_l][c_l] = src[(size_t)c_l * HW + px_l];
    }
    __syncthreads();
    int px_l = t >> 2, cg = t & 3;
    int p = b * HW + pxt * 64 + px_l;
    float m = meanb[p], rs = rstdb[p];
    size_t ob = (size_t)p * C0 + ct * 64 + cg * 16;
    short8 h0, h1, l0, l1;
    for (int j = 0; j < 8; ++j) {
        int c = ct * 64 + cg * 16 + j;
        float f = (tile[px_l][cg * 16 + j] - m) * rs * gam[c] + bet[c];
        ushort h = f2bf(f);
        h0[j] = (short)h; l0[j] = (short)f2bf(f - bf2f(h));
        c = ct * 64 + cg * 16 + 8 + j;
        f = (tile[px_l][cg * 16 + 8 + j] - m) * rs * gam[c] + bet[c];
        h = f2bf(f);
        h1[j] = (short)h; l1[j] = (short)f2bf(f - bf2f(h));
    }
    *(short8*)(Xhi + ob) = h0; *(short8*)(Xhi + ob + 8) = h1;
    *(short8*)(Xlo + ob) = l0; *(short8*)(Xlo + ob + 8) = l1;
}

// ---------------------------------------------------------------- corr ------
// wave per pixel; lane owns 4 channels; 49 per-lane accumulators; one batched
// reduction at the end (shfl x2 + LDS transpose).
__global__ __launch_bounds__(256) void corr_kernel(
    const ushort* __restrict__ x1c, const ushort* __restrict__ x2c,
    ushort* __restrict__ Xhi, ushort* __restrict__ Xlo) {
    __shared__ float red[4][49][20];
    int wid = (blockIdx.x * blockDim.x + threadIdx.x) >> 6;
    int lane = threadIdx.x & 63;
    int wv = threadIdx.x >> 6;
    if (wid >= NPIX) return;
    int b = wid / HW, rem = wid % HW, y = rem / WW_, x = rem % WW_;
    const ushort* A0 = x1c + (size_t)b * HW * CC + lane * 4;
    const ushort* B0 = x2c + (size_t)b * HW * CC + lane * 4;

    float acc[49];
#pragma unroll
    for (int d = 0; d < 49; ++d) acc[d] = 0.f;

#pragma unroll
    for (int d = 0; d < 49; ++d) {
        const int dy = d / 7 - 3, dx = d % 7 - 3;
        int ay = y - dy, ax = x - dx, by = y + dy, bx = x + dx;
        if ((unsigned)ay < 96u && (unsigned)ax < 160u &&
            (unsigned)by < 96u && (unsigned)bx < 160u) {
            uint2 av = *(const uint2*)(A0 + (size_t)(ay * WW_ + ax) * CC);
            uint2 bv = *(const uint2*)(B0 + (size_t)(by * WW_ + bx) * CC);
            float s = bfbits_lo(av.x) * bfbits_lo(bv.x);
            s += bfbits_hi(av.x) * bfbits_hi(bv.x);
            s += bfbits_lo(av.y) * bfbits_lo(bv.y);
            s += bfbits_hi(av.y) * bfbits_hi(bv.y);
            acc[d] += s;
        }
    }
    // batched reduce: 64 lanes -> 16 partials per d -> LDS -> lane d sums 16
#pragma unroll
    for (int d = 0; d < 49; ++d) {
        float v = acc[d];
        v += __shfl_xor(v, 32);
        v += __shfl_xor(v, 16);
        if (lane < 16) red[wv][d][lane] = v;
    }
    float v = 0.f;
    if (lane < 49) {
#pragma unroll
        for (int g = 0; g < 4; ++g) {
            f32x4 r = *(const f32x4*)&red[wv][lane][g * 4];
            v += (r[0] + r[1]) + (r[2] + r[3]);
        }
    }
    ushort h = f2bf(v);
    size_t o = (size_t)wid * C0 + 256 + lane;
    Xhi[o] = h;
    Xlo[o] = f2bf(v - bf2f(h));
}

// ------------------------------------------------------------ weight pack ---
__global__ void pack_w_kernel(const float* __restrict__ w, int CinReal, int KC, int isDeconv,
                              ushort* __restrict__ whi, ushort* __restrict__ wlo) {
    int gid = blockIdx.x * blockDim.x + threadIdx.x;
    int total = 9 * KC * 4 * 64;
    if (gid >= total) return;
    int lane = gid & 63;
    int nt = (gid >> 6) & 3;
    int kc = (gid >> 8) % KC;
    int slot = (gid >> 8) / KC;
    int co = nt * 16 + (lane & 15);
    int ky = slot / 3, kx = slot % 3;
    for (int j = 0; j < 8; ++j) {
        int ci = kc * 32 + (lane >> 4) * 8 + j;
        float v = 0.f;
        if (ci < CinReal) {
            if (isDeconv) v = w[((size_t)(ci * 64 + co) * 3 + (2 - ky)) * 3 + (2 - kx)];
            else          v = w[((size_t)(co * CinReal + ci) * 3 + ky) * 3 + kx];
        }
        ushort h = f2bf(v);
        whi[(size_t)gid * 8 + j] = h;
        wlo[(size_t)gid * 8 + j] = f2bf(v - bf2f(h));
    }
}

// -------------------------------------------------------- MFMA conv core ----
struct TapList { int dy[9]; int dx[9]; int slot[9]; int n; };

__global__ __launch_bounds__(256) void conv_mfma_kernel(
    const ushort* __restrict__ Ahi, const ushort* __restrict__ Alo,
    int CIN, int KC,
    const ushort* __restrict__ Whi, const ushort* __restrict__ Wlo,
    const float* __restrict__ bias,
    TapList taps,
    ushort* __restrict__ Ohi, ushort* __restrict__ Olo,
    const ushort* __restrict__ Rhi, const ushort* __restrict__ Rlo,
    float slope, int act, int hasres) {
    const int lane = threadIdx.x & 63;
    const int wave = threadIdx.x >> 6;
    const int kg = lane >> 4;
    const int tileBase = (blockIdx.x * 4 + wave) * 16;
    const short8 zero8 = {0, 0, 0, 0, 0, 0, 0, 0};

    int pm = tileBase + (lane & 15);
    int b0 = pm / HW, r0 = pm % HW, y0 = r0 / WW_, x0 = r0 % WW_;

    f32x4 acc[4];
#pragma unroll
    for (int nt = 0; nt < 4; ++nt) acc[nt] = (f32x4){0.f, 0.f, 0.f, 0.f};

    for (int t = 0; t < taps.n; ++t) {
        int dy = taps.dy[t], dx = taps.dx[t];
        int yy = y0 + dy, xx = x0 + dx;
        bool v = (unsigned)yy < 96u && (unsigned)xx < 160u;
        int yyc = min(max(yy, 0), 95), xxc = min(max(xx, 0), 159);
        size_t a = ((size_t)b0 * HW + yyc * WW_ + xxc) * (size_t)CIN + kg * 8;
        const ushort* wh_t = Whi + (size_t)taps.slot[t] * KC * 2048;
        const ushort* wl_t = Wlo + (size_t)taps.slot[t] * KC * 2048;
        for (int kc = 0; kc < KC; ++kc) {
            short8 ah = *(const short8*)(Ahi + a + kc * 32);
            short8 al = *(const short8*)(Alo + a + kc * 32);
            if (!v) { ah = zero8; al = zero8; }
#pragma unroll
            for (int nt = 0; nt < 4; ++nt) {
                size_t wo = (((size_t)kc * 4 + nt) * 64 + lane) * 8;
                short8 bh = *(const short8*)(wh_t + wo);
                short8 bl = *(const short8*)(wl_t + wo);
                acc[nt] = __builtin_amdgcn_mfma_f32_16x16x32_bf16(ah, bh, acc[nt], 0, 0, 0);
                acc[nt] = __builtin_amdgcn_mfma_f32_16x16x32_bf16(al, bh, acc[nt], 0, 0, 0);
                acc[nt] = __builtin_amdgcn_mfma_f32_16x16x32_bf16(ah, bl, acc[nt], 0, 0, 0);
            }
        }
    }

#pragma unroll
    for (int r = 0; r < 4; ++r) {
        int pr = tileBase + kg * 4 + r;
#pragma unroll
        for (int nt = 0; nt < 4; ++nt) {
            int co = nt * 16 + (lane & 15);
            float vv = acc[nt][r] + bias[co];
            size_t oo = (size_t)pr * 64 + co;
            if (hasres) vv += bf2f(Rhi[oo]) + bf2f(Rlo[oo]);
            if (act) vv = vv >= 0.f ? vv : vv * slope;
            ushort h = f2bf(vv);
            Ohi[oo] = h;
            Olo[oo] = f2bf(vv - bf2f(h));
        }
    }
}

// ------------------------------------------- fused transposed conv (4 par) --
__global__ __launch_bounds__(256) void deconv_fused_kernel(
    const ushort* __restrict__ Ahi, const ushort* __restrict__ Alo,
    const ushort* __restrict__ Whi, const ushort* __restrict__ Wlo,
    const float* __restrict__ bias,
    ushort* __restrict__ Ohi, ushort* __restrict__ Olo) {
    const int lane = threadIdx.x & 63;
    const int wave = threadIdx.x >> 6;
    const int kg = lane >> 4;
    const int tileBase = (blockIdx.x * 4 + wave) * 16;
    const short8 zero8 = {0, 0, 0, 0, 0, 0, 0, 0};

    int pm = tileBase + (lane & 15);
    int b0 = pm / HW, r0 = pm % HW, y0 = r0 / WW_, x0 = r0 % WW_;

    f32x4 acc[4][4];   // [parity][nt]
#pragma unroll
    for (int p = 0; p < 4; ++p)
#pragma unroll
        for (int nt = 0; nt < 4; ++nt) acc[p][nt] = (f32x4){0.f, 0.f, 0.f, 0.f};

    // offset -> (parity, slot) lists
    const int nuse[4]   = {4, 2, 2, 1};
    const int upar[4][4] = {{0, 1, 2, 3}, {1, 3, -1, -1}, {2, 3, -1, -1}, {3, -1, -1, -1}};
    const int uslt[4][4] = {{4, 3, 1, 0}, {5, 2, -1, -1}, {7, 6, -1, -1}, {8, -1, -1, -1}};

#pragma unroll
    for (int o = 0; o < 4; ++o) {
        const int ody = o >> 1, odx = o & 1;
        int yy = y0 + ody, xx = x0 + odx;
        bool v = (unsigned)yy < 96u && (unsigned)xx < 160u;
        int yyc = min(yy, 95), xxc = min(xx, 159);
        size_t a = ((size_t)b0 * HW + yyc * WW_ + xxc) * 64 + kg * 8;
        for (int kc = 0; kc < 2; ++kc) {
            short8 ah = *(const short8*)(Ahi + a + kc * 32);
            short8 al = *(const short8*)(Alo + a + kc * 32);
            if (!v) { ah = zero8; al = zero8; }
#pragma unroll
            for (int u = 0; u < 4; ++u) {
                if (u >= nuse[o]) break;
                int par = upar[o][u], slot = uslt[o][u];
#pragma unroll
                for (int nt = 0; nt < 4; ++nt) {
                    size_t wo = ((size_t)slot * 2 + kc) * 2048 + ((size_t)nt * 64 + lane) * 8;
                    short8 bh = *(const short8*)(Whi + wo);
                    short8 bl = *(const short8*)(Wlo + wo);
                    acc[par][nt] = __builtin_amdgcn_mfma_f32_16x16x32_bf16(ah, bh, acc[par][nt], 0, 0, 0);
                    acc[par][nt] = __builtin_amdgcn_mfma_f32_16x16x32_bf16(al, bh, acc[par][nt], 0, 0, 0);
                    acc[par][nt] = __builtin_amdgcn_mfma_f32_16x16x32_bf16(ah, bl, acc[par][nt], 0, 0, 0);
                }
            }
        }
    }

#pragma unroll
    for (int r = 0; r < 4; ++r) {
        int pr = tileBase + kg * 4 + r;
        int b2 = pr / HW, rr = pr % HW, y2 = rr / WW_, x2 = rr % WW_;
#pragma unroll
        for (int par = 0; par < 4; ++par) {
            int py = par >> 1, px = par & 1;
            size_t po = ((size_t)b2 * H2 + 2 * y2 + py) * W2 + 2 * x2 + px;
#pragma unroll
            for (int nt = 0; nt < 4; ++nt) {
                int co = nt * 16 + (lane & 15);
                float vv = acc[par][nt][r] + bias[co];
                size_t oo = po * 64 + co;
                ushort h = f2bf(vv);
                Ohi[oo] = h;
                Olo[oo] = f2bf(vv - bf2f(h));
            }
        }
    }
}

// ---------------------------------------------------------------- flow ------
__global__ __launch_bounds__(256) void flow_kernel(const ushort* __restrict__ dechi,
                                                   const ushort* __restrict__ declo,
                                                   const float* __restrict__ wf,
                                                   const float* __restrict__ bf2v,
                                                   float* __restrict__ flow) {
    __shared__ float wsm[1152];
    for (int i = threadIdx.x; i < 1152; i += 256) wsm[i] = wf[i];
    __syncthreads();
    int p = blockIdx.x * 256 + threadIdx.x;
    if (p >= 4 * OHW) return;
    int b = p / OHW, rem = p % OHW, oy = rem / W2, ox = rem % W2;
    float a0 = bf2v[0], a1 = bf2v[1];
    for (int ky = 0; ky < 3; ++ky) {
        int yy = oy + ky - 1;
        if ((unsigned)yy >= (unsigned)H2) continue;
        for (int kx = 0; kx < 3; ++kx) {
            int xx = ox + kx - 1;
            if ((unsigned)xx >= (unsigned)W2) continue;
            size_t base = ((size_t)b * OHW + yy * W2 + xx) * 64;
            int tap = ky * 3 + kx;
            for (int c4 = 0; c4 < 16; ++c4) {
                unsigned long long h8 = *(const unsigned long long*)(dechi + base + c4 * 4);
                unsigned long long l8 = *(const unsigned long long*)(declo + base + c4 * 4);
                for (int j = 0; j < 4; ++j) {
                    float f = bf2f((ushort)(h8 >> (16 * j))) + bf2f((ushort)(l8 >> (16 * j)));
                    int ci = c4 * 4 + j;
                    a0 += f * wsm[ci * 9 + tap];
                    a1 += f * wsm[(64 + ci) * 9 + tap];
                }
            }
        }
    }
    flow[(size_t)(b * 2 + 0) * OHW + rem] = a0;
    flow[(size_t)(b * 2 + 1) * OHW + rem] = a1;
}

// --------------------------------------------------------------- resize -----
__global__ void resize_kernel(const float* __restrict__ flow, float* __restrict__ out) {
    int idx = blockIdx.x * blockDim.x + threadIdx.x;
    int total = 4 * 2 * HO * WO;
    if (idx >= total) return;
    int ox = idx % WO;
    int oy = (idx / WO) % HO;
    int c = (idx / (WO * HO)) % 2;
    int b = idx / (WO * HO * 2);
    float sy = (oy + 0.5f) * 0.25f - 0.5f;
    float sx = (ox + 0.5f) * 0.25f - 0.5f;
    int y0 = (int)floorf(sy);
    int x0 = (int)floorf(sx);
    float fy = sy - y0;
    float fx = sx - x0;
    int y0c = min(max(y0, 0), H2 - 1);
    int y1c = min(max(y0 + 1, 0), H2 - 1);
    int x0c = min(max(x0, 0), W2 - 1);
    int x1c = min(max(x0 + 1, 0), W2 - 1);
    const float* fb = flow + (size_t)(b * 2 + c) * OHW;
    float v00 = fb[y0c * W2 + x0c];
    float v01 = fb[y0c * W2 + x1c];
    float v10 = fb[y1c * W2 + x0c];
    float v11 = fb[y1c * W2 + x1c];
    float v = (1.f - fy) * ((1.f - fx) * v00 + fx * v01)
            + fy * ((1.f - fx) * v10 + fx * v11);
    out[idx] = v * 4.0f;
}

// =================================================================== host ===
extern "C" void kernel_launch(void* const* d_in, const int* in_sizes, int n_in,
                              void* d_out, int out_size, void* d_ws, size_t ws_size,
                              hipStream_t stream) {
    const float* x1   = (const float*)d_in[0];
    const float* x2   = (const float*)d_in[1];
    const float* xt   = (const float*)d_in[2];
    const float* gln  = (const float*)d_in[3];
    const float* bln  = (const float*)d_in[4];
    const float* w0   = (const float*)d_in[5];
    const float* b0   = (const float*)d_in[6];
    const float* wr1  = (const float*)d_in[7];
    const float* br1  = (const float*)d_in[8];
    const float* wr2  = (const float*)d_in[9];
    const float* br2  = (const float*)d_in[10];
    const float* w2   = (const float*)d_in[11];
    const float* b2   = (const float*)d_in[12];
    const float* w3   = (const float*)d_in[13];
    const float* b3   = (const float*)d_in[14];
    const float* wdec = (const float*)d_in[15];
    const float* bdec = (const float*)d_in[16];
    const float* wf   = (const float*)d_in[17];
    const float* bfv  = (const float*)d_in[18];
    float* out = (float*)d_out;

    char* ws = (char*)d_ws;
    float*  inv1  = (float*)(ws + 0);
    float*  inv2  = (float*)(ws + 245760);
    float*  meanb = (float*)(ws + 491520);
    float*  rstdb = (float*)(ws + 737280);
    ushort* x1c   = (ushort*)(ws + 1048576);
    ushort* x2c   = (ushort*)(ws + 1048576 + 31457280);
    ushort* X0hi  = (ushort*)(ws + 67108864);
    ushort* X0lo  = (ushort*)(ws + 106430464);
    const size_t P = 7864320;
    ushort* y0hi = (ushort*)(ws + 1048576 + 0 * P);
    ushort* y0lo = (ushort*)(ws + 1048576 + 1 * P);
    ushort* t1hi = (ushort*)(ws + 1048576 + 2 * P);
    ushort* t1lo = (ushort*)(ws + 1048576 + 3 * P);
    ushort* t2hi = (ushort*)(ws + 1048576 + 4 * P);
    ushort* t2lo = (ushort*)(ws + 1048576 + 5 * P);
    ushort* dechi = (ushort*)(ws + 67108864);
    ushort* declo = (ushort*)(ws + 98566144);
    float*  flowb = (float*)(ws + 130023424);
    char* wp = ws + 146800640;
    ushort* W0hi  = (ushort*)(wp);             ushort* W0lo  = (ushort*)(wp + 368640);
    ushort* WR1hi = (ushort*)(wp + 737280);    ushort* WR1lo = (ushort*)(wp + 737280 + 73728);
    ushort* WR2hi = (ushort*)(wp + 884736);    ushort* WR2lo = (ushort*)(wp + 884736 + 73728);
    ushort* W2hi  = (ushort*)(wp + 1032192);   ushort* W2lo  = (ushort*)(wp + 1032192 + 73728);
    ushort* W3hi  = (ushort*)(wp + 1179648);   ushort* W3lo  = (ushort*)(wp + 1179648 + 73728);
    ushort* WDhi  = (ushort*)(wp + 1327104);   ushort* WDlo  = (ushort*)(wp + 1327104 + 73728);

    TapList T9; T9.n = 9;
    for (int ky = 0; ky < 3; ++ky)
        for (int kx = 0; kx < 3; ++kx) {
            int i = ky * 3 + kx;
            T9.dy[i] = ky - 1; T9.dx[i] = kx - 1; T9.slot[i] = i;
        }

    pack_w_kernel<<<90, 256, 0, stream>>>(w0, 305, 10, 0, W0hi, W0lo);
    pack_w_kernel<<<18, 256, 0, stream>>>(wr1, 64, 2, 0, WR1hi, WR1lo);
    pack_w_kernel<<<18, 256, 0, stream>>>(wr2, 64, 2, 0, WR2hi, WR2lo);
    pack_w_kernel<<<18, 256, 0, stream>>>(w2, 64, 2, 0, W2hi, W2lo);
    pack_w_kernel<<<18, 256, 0, stream>>>(w3, 64, 2, 0, W3hi, W3lo);
    pack_w_kernel<<<18, 256, 0, stream>>>(wdec, 64, 2, 1, WDhi, WDlo);

    stats_kernel<<<960, 256, 0, stream>>>(x1, x2, xt, inv1, inv2, meanb, rstdb);
    pack_x_kernel<<<dim3(240, 4, 4), 256, 0, stream>>>(x1, inv1, x1c);
    pack_x_kernel<<<dim3(240, 4, 4), 256, 0, stream>>>(x2, inv2, x2c);
    pack_ln_kernel<<<dim3(240, 4, 4), 256, 0, stream>>>(xt, gln, bln, meanb, rstdb, X0hi, X0lo);
    corr_kernel<<<15360, 256, 0, stream>>>(x1c, x2c, X0hi, X0lo);

    conv_mfma_kernel<<<960, 256, 0, stream>>>(X0hi, X0lo, C0, 10, W0hi, W0lo, b0, T9,
        y0hi, y0lo, nullptr, nullptr, 0.f, 0, 0);
    conv_mfma_kernel<<<960, 256, 0, stream>>>(y0hi, y0lo, 64, 2, WR1hi, WR1lo, br1, T9,
        t1hi, t1lo, nullptr, nullptr, 0.1f, 1, 0);
    conv_mfma_kernel<<<960, 256, 0, stream>>>(t1hi, t1lo, 64, 2, WR2hi, WR2lo, br2, T9,
        t2hi, t2lo, y0hi, y0lo, 0.1f, 1, 1);
    conv_mfma_kernel<<<960, 256, 0, stream>>>(t2hi, t2lo, 64, 2, W2hi, W2lo, b2, T9,
        t1hi, t1lo, nullptr, nullptr, 0.2f, 1, 0);
    conv_mfma_kernel<<<960, 256, 0, stream>>>(t1hi, t1lo, 64, 2, W3hi, W3lo, b3, T9,
        t2hi, t2lo, nullptr, nullptr, 0.2f, 1, 0);
    deconv_fused_kernel<<<960, 256, 0, stream>>>(t2hi, t2lo, WDhi, WDlo, bdec, dechi, declo);

    flow_kernel<<<960, 256, 0, stream>>>(dechi, declo, wf, bfv, flowb);
    resize_kernel<<<30720, 256, 0, stream>>>(flowb, out);

    (void)in_sizes; (void)n_in; (void)out_size; (void)ws_size;
}

// Round 4
// 632.787 us; speedup vs baseline: 1.5007x; 1.5007x over previous
//
#include <hip/hip_runtime.h>
#include <math.h>

#define HH_ 96
#define WW_ 160
#define HW 15360          // 96*160
#define NPIX 61440        // 4*HW
#define CC 256
#define C0 320            // padded conv0 Cin
#define FF 64
#define H2 192
#define W2 320
#define OHW 61440         // 192*320
#define HO 768
#define WO 1280

typedef __attribute__((ext_vector_type(8))) short short8;
typedef __attribute__((ext_vector_type(4))) float f32x4;

__device__ __forceinline__ float bf2f(ushort u) {
    union { unsigned int i; float f; } v; v.i = ((unsigned int)u) << 16; return v.f;
}
__device__ __forceinline__ ushort f2bf(float f) {
    union { float f; unsigned int i; } v; v.f = f;
    unsigned int u = v.i;
    return (ushort)((u + 0x7FFFu + ((u >> 16) & 1u)) >> 16);
}

// ---------------- fused stats + normalize/LN + NHWC bf16 pack ---------------
// blockIdx.y: 0 -> x1 (l2norm, to x1c), 1 -> x2 (l2norm, to x2c),
//             2 -> xt (layernorm, hi/lo to X0, zero-fill ch 256..319)
__global__ __launch_bounds__(256) void normpack_kernel(
    const float* __restrict__ x1, const float* __restrict__ x2, const float* __restrict__ xt,
    const float* __restrict__ gam, const float* __restrict__ bet,
    ushort* __restrict__ x1c, ushort* __restrict__ x2c,
    ushort* __restrict__ Xhi, ushort* __restrict__ Xlo) {
    __shared__ float tile[32 * 257];
    const int t = threadIdx.x;
    const int pxt = blockIdx.x, which = blockIdx.y, b = blockIdx.z;
    const float* src = (which == 0 ? x1 : which == 1 ? x2 : xt);
    src += (size_t)b * CC * HW + pxt * 32;

    // load 32 px x 256 ch into LDS (f32)
    {
        int px_l = t & 31, c_hi = t >> 5;   // c_hi 0..7
#pragma unroll 8
        for (int i = 0; i < 32; ++i) {
            int c = i * 8 + c_hi;
            tile[px_l * 257 + c] = src[(size_t)c * HW + px_l];
        }
    }
    __syncthreads();

    const int px = t >> 3, oct = t & 7;     // 32 px, 8 threads each (32 ch)
    float s1 = 0.f, s2 = 0.f;
    {
        const float* row = &tile[px * 257];
#pragma unroll
        for (int i = 0; i < 32; ++i) {
            int cc = oct * 32 + ((i + oct * 4) & 31);   // staggered, conflict-light
            float v = row[cc];
            s1 += v; s2 += v * v;
        }
    }
    s1 += __shfl_xor(s1, 1); s1 += __shfl_xor(s1, 2); s1 += __shfl_xor(s1, 4);
    s2 += __shfl_xor(s2, 1); s2 += __shfl_xor(s2, 2); s2 += __shfl_xor(s2, 4);

    const int p = b * HW + pxt * 32 + px;
    const float* row = &tile[px * 257];
    if (which < 2) {
        float inv = 1.f / fmaxf(sqrtf(s2), 1e-12f);
        ushort* dst = (which == 0 ? x1c : x2c);
        size_t ob = (size_t)p * CC + oct * 32;
#pragma unroll
        for (int g = 0; g < 4; ++g) {
            short8 v;
#pragma unroll
            for (int j = 0; j < 8; ++j)
                v[j] = (short)f2bf(row[oct * 32 + g * 8 + j] * inv);
            *(short8*)(dst + ob + g * 8) = v;
        }
    } else {
        float m = s1 * (1.f / 256.f);
        float var = fmaxf(s2 * (1.f / 256.f) - m * m, 0.f);
        float rs = rsqrtf(var + 1e-5f);
        size_t ob = (size_t)p * C0 + oct * 32;
#pragma unroll
        for (int g = 0; g < 4; ++g) {
            short8 vh, vl;
#pragma unroll
            for (int j = 0; j < 8; ++j) {
                int c = oct * 32 + g * 8 + j;
                float f = (row[c] - m) * rs * gam[c] + bet[c];
                ushort h = f2bf(f);
                vh[j] = (short)h;
                vl[j] = (short)f2bf(f - bf2f(h));
            }
            *(short8*)(Xhi + ob + g * 8) = vh;
            *(short8*)(Xlo + ob + g * 8) = vl;
        }
        // zero-fill corr channels 256..319 (8 ch per thread)
        short8 z = {0, 0, 0, 0, 0, 0, 0, 0};
        size_t zb = (size_t)p * C0 + 256 + oct * 8;
        *(short8*)(Xhi + zb) = z;
        *(short8*)(Xlo + zb) = z;
    }
}

// ---------------------------------------------------------------- corr ------
// MFMA band-matmul: tile = 16 queries (row u, x0..x0+15) from x1n.
// For each dy: keys = x2n row u+2dy, x in [x0-6, x0+25]; P = Q·K^T (16x32);
// out[(u+dy, qx+dx), (dy,dx)] = P[q, q+2dx+6].
__global__ __launch_bounds__(256) void corr_mfma_kernel(
    const ushort* __restrict__ x1c, const ushort* __restrict__ x2c,
    ushort* __restrict__ Xhi, ushort* __restrict__ Xlo) {
    const int lane = threadIdx.x & 63;
    const int wv = threadIdx.x >> 6;
    const int tile = blockIdx.x * 4 + wv;          // 3840 tiles
    const int xt = tile % 10;
    const int u  = (tile / 10) % HH_;
    const int b  = tile / (10 * HH_);
    const int x0 = xt * 16;
    const int jl = lane & 15;
    const int kg = lane >> 4;
    const short8 zero8 = {0, 0, 0, 0, 0, 0, 0, 0};

    // resident Q fragments (8 k-steps)
    short8 qf[8];
    {
        size_t qb = ((size_t)b * HW + u * WW_ + x0 + jl) * CC + kg * 8;
#pragma unroll
        for (int ks = 0; ks < 8; ++ks)
            qf[ks] = *(const short8*)(x1c + qb + ks * 32);
    }

    for (int dy = -3; dy <= 3; ++dy) {
        const int y = u + dy;
        if ((unsigned)y >= (unsigned)HH_) continue;     // no outputs this dy
        const int w = u + 2 * dy;
        const bool rowok = (unsigned)w < (unsigned)HH_;

        f32x4 acc0 = (f32x4){0.f, 0.f, 0.f, 0.f};
        f32x4 acc1 = (f32x4){0.f, 0.f, 0.f, 0.f};
        if (rowok) {
#pragma unroll
            for (int nt = 0; nt < 2; ++nt) {
                int kx = x0 - 6 + jl + 16 * nt;
                bool ok = (unsigned)kx < (unsigned)WW_;
                int kxc = min(max(kx, 0), WW_ - 1);
                size_t kb = ((size_t)b * HW + w * WW_ + kxc) * CC + kg * 8;
#pragma unroll
                for (int ks = 0; ks < 8; ++ks) {
                    short8 bv = *(const short8*)(x2c + kb + ks * 32);
                    if (!ok) bv = zero8;
                    if (nt == 0)
                        acc0 = __builtin_amdgcn_mfma_f32_16x16x32_bf16(qf[ks], bv, acc0, 0, 0, 0);
                    else
                        acc1 = __builtin_amdgcn_mfma_f32_16x16x32_bf16(qf[ks], bv, acc1, 0, 0, 0);
                }
            }
        }
        // band extract + store: lane owns col j = jl + 16*nt, rows q = kg*4+r
#pragma unroll
        for (int nt = 0; nt < 2; ++nt) {
            int j = jl + 16 * nt;
#pragma unroll
            for (int r = 0; r < 4; ++r) {
                int q = kg * 4 + r;
                int tt = j - q - 6;
                if (tt & 1) continue;
                int dx = tt >> 1;
                if (dx < -3 || dx > 3) continue;
                int cx = x0 + q + dx;
                if ((unsigned)cx >= (unsigned)WW_) continue;
                float v = rowok ? (nt == 0 ? acc0[r] : acc1[r]) : 0.f;
                size_t o = ((size_t)(b * HW + y * WW_ + cx)) * C0
                         + 256 + (dy + 3) * 7 + (dx + 3);
                ushort h = f2bf(v);
                Xhi[o] = h;
                Xlo[o] = f2bf(v - bf2f(h));
            }
        }
    }
}

// ------------------------------------------------------------ weight pack ---
__global__ void pack_w_kernel(const float* __restrict__ w, int CinReal, int KC, int isDeconv,
                              ushort* __restrict__ whi, ushort* __restrict__ wlo) {
    int gid = blockIdx.x * blockDim.x + threadIdx.x;
    int total = 9 * KC * 4 * 64;
    if (gid >= total) return;
    int lane = gid & 63;
    int nt = (gid >> 6) & 3;
    int kc = (gid >> 8) % KC;
    int slot = (gid >> 8) / KC;
    int co = nt * 16 + (lane & 15);
    int ky = slot / 3, kx = slot % 3;
    for (int j = 0; j < 8; ++j) {
        int ci = kc * 32 + (lane >> 4) * 8 + j;
        float v = 0.f;
        if (ci < CinReal) {
            if (isDeconv) v = w[((size_t)(ci * 64 + co) * 3 + (2 - ky)) * 3 + (2 - kx)];
            else          v = w[((size_t)(co * CinReal + ci) * 3 + ky) * 3 + kx];
        }
        ushort h = f2bf(v);
        whi[(size_t)gid * 8 + j] = h;
        wlo[(size_t)gid * 8 + j] = f2bf(v - bf2f(h));
    }
}

// -------------------------------------------------------- MFMA conv core ----
struct TapList { int dy[9]; int dx[9]; int slot[9]; int n; };

__global__ __launch_bounds__(256) void conv_mfma_kernel(
    const ushort* __restrict__ Ahi, const ushort* __restrict__ Alo,
    int CIN, int KC,
    const ushort* __restrict__ Whi, const ushort* __restrict__ Wlo,
    const float* __restrict__ bias,
    TapList taps,
    ushort* __restrict__ Ohi, ushort* __restrict__ Olo,
    const ushort* __restrict__ Rhi, const ushort* __restrict__ Rlo,
    float slope, int act, int hasres) {
    const int lane = threadIdx.x & 63;
    const int wave = threadIdx.x >> 6;
    const int kg = lane >> 4;
    const int tileBase = (blockIdx.x * 4 + wave) * 32;
    const short8 zero8 = {0, 0, 0, 0, 0, 0, 0, 0};

    int pm0 = tileBase + (lane & 15);
    int pm1 = pm0 + 16;
    int b0 = pm0 / HW, r0 = pm0 % HW, y0 = r0 / WW_, x0 = r0 % WW_;
    int b1 = pm1 / HW, r1 = pm1 % HW, y1 = r1 / WW_, x1 = r1 % WW_;

    f32x4 acc[2][4];
    for (int s = 0; s < 2; ++s)
        for (int nt = 0; nt < 4; ++nt)
            acc[s][nt] = (f32x4){0.f, 0.f, 0.f, 0.f};

    for (int t = 0; t < taps.n; ++t) {
        int dy = taps.dy[t], dx = taps.dx[t];
        int yy0 = y0 + dy, xx0 = x0 + dx, yy1 = y1 + dy, xx1 = x1 + dx;
        bool v0 = (unsigned)yy0 < 96u && (unsigned)xx0 < 160u;
        bool v1 = (unsigned)yy1 < 96u && (unsigned)xx1 < 160u;
        int yy0c = min(max(yy0, 0), 95), xx0c = min(max(xx0, 0), 159);
        int yy1c = min(max(yy1, 0), 95), xx1c = min(max(xx1, 0), 159);
        size_t a0 = ((size_t)b0 * HW + yy0c * WW_ + xx0c) * (size_t)CIN + kg * 8;
        size_t a1 = ((size_t)b1 * HW + yy1c * WW_ + xx1c) * (size_t)CIN + kg * 8;
        const ushort* wh_t = Whi + (size_t)taps.slot[t] * KC * 2048;
        const ushort* wl_t = Wlo + (size_t)taps.slot[t] * KC * 2048;
        for (int kc = 0; kc < KC; ++kc) {
            short8 ah0 = *(const short8*)(Ahi + a0 + kc * 32);
            short8 al0 = *(const short8*)(Alo + a0 + kc * 32);
            short8 ah1 = *(const short8*)(Ahi + a1 + kc * 32);
            short8 al1 = *(const short8*)(Alo + a1 + kc * 32);
            if (!v0) { ah0 = zero8; al0 = zero8; }
            if (!v1) { ah1 = zero8; al1 = zero8; }
#pragma unroll
            for (int nt = 0; nt < 4; ++nt) {
                size_t wo = (((size_t)kc * 4 + nt) * 64 + lane) * 8;
                short8 bh = *(const short8*)(wh_t + wo);
                short8 bl = *(const short8*)(wl_t + wo);
                acc[0][nt] = __builtin_amdgcn_mfma_f32_16x16x32_bf16(ah0, bh, acc[0][nt], 0, 0, 0);
                acc[1][nt] = __builtin_amdgcn_mfma_f32_16x16x32_bf16(ah1, bh, acc[1][nt], 0, 0, 0);
                acc[0][nt] = __builtin_amdgcn_mfma_f32_16x16x32_bf16(al0, bh, acc[0][nt], 0, 0, 0);
                acc[1][nt] = __builtin_amdgcn_mfma_f32_16x16x32_bf16(al1, bh, acc[1][nt], 0, 0, 0);
                acc[0][nt] = __builtin_amdgcn_mfma_f32_16x16x32_bf16(ah0, bl, acc[0][nt], 0, 0, 0);
                acc[1][nt] = __builtin_amdgcn_mfma_f32_16x16x32_bf16(ah1, bl, acc[1][nt], 0, 0, 0);
            }
        }
    }

    for (int s = 0; s < 2; ++s) {
        for (int r = 0; r < 4; ++r) {
            int pr = tileBase + s * 16 + kg * 4 + r;
            for (int nt = 0; nt < 4; ++nt) {
                int co = nt * 16 + (lane & 15);
                float vv = acc[s][nt][r] + bias[co];
                size_t oo = (size_t)pr * 64 + co;
                if (hasres) vv += bf2f(Rhi[oo]) + bf2f(Rlo[oo]);
                if (act) vv = vv >= 0.f ? vv : vv * slope;
                ushort h = f2bf(vv);
                Ohi[oo] = h;
                Olo[oo] = f2bf(vv - bf2f(h));
            }
        }
    }
}

// ------------------------------------------- fused transposed conv (4 par) --
__global__ __launch_bounds__(256) void deconv_fused_kernel(
    const ushort* __restrict__ Ahi, const ushort* __restrict__ Alo,
    const ushort* __restrict__ Whi, const ushort* __restrict__ Wlo,
    const float* __restrict__ bias,
    ushort* __restrict__ Ohi, ushort* __restrict__ Olo) {
    const int lane = threadIdx.x & 63;
    const int wave = threadIdx.x >> 6;
    const int kg = lane >> 4;
    const int tileBase = (blockIdx.x * 4 + wave) * 16;
    const short8 zero8 = {0, 0, 0, 0, 0, 0, 0, 0};

    int pm = tileBase + (lane & 15);
    int b0 = pm / HW, r0 = pm % HW, y0 = r0 / WW_, x0 = r0 % WW_;

    f32x4 acc[4][4];   // [parity][nt]
#pragma unroll
    for (int p = 0; p < 4; ++p)
#pragma unroll
        for (int nt = 0; nt < 4; ++nt) acc[p][nt] = (f32x4){0.f, 0.f, 0.f, 0.f};

    const int nuse[4]   = {4, 2, 2, 1};
    const int upar[4][4] = {{0, 1, 2, 3}, {1, 3, -1, -1}, {2, 3, -1, -1}, {3, -1, -1, -1}};
    const int uslt[4][4] = {{4, 3, 1, 0}, {5, 2, -1, -1}, {7, 6, -1, -1}, {8, -1, -1, -1}};

#pragma unroll
    for (int o = 0; o < 4; ++o) {
        const int ody = o >> 1, odx = o & 1;
        int yy = y0 + ody, xx = x0 + odx;
        bool v = (unsigned)yy < 96u && (unsigned)xx < 160u;
        int yyc = min(yy, 95), xxc = min(xx, 159);
        size_t a = ((size_t)b0 * HW + yyc * WW_ + xxc) * 64 + kg * 8;
        for (int kc = 0; kc < 2; ++kc) {
            short8 ah = *(const short8*)(Ahi + a + kc * 32);
            short8 al = *(const short8*)(Alo + a + kc * 32);
            if (!v) { ah = zero8; al = zero8; }
#pragma unroll
            for (int u = 0; u < 4; ++u) {
                if (u >= nuse[o]) break;
                int par = upar[o][u], slot = uslt[o][u];
#pragma unroll
                for (int nt = 0; nt < 4; ++nt) {
                    size_t wo = ((size_t)slot * 2 + kc) * 2048 + ((size_t)nt * 64 + lane) * 8;
                    short8 bh = *(const short8*)(Whi + wo);
                    short8 bl = *(const short8*)(Wlo + wo);
                    acc[par][nt] = __builtin_amdgcn_mfma_f32_16x16x32_bf16(ah, bh, acc[par][nt], 0, 0, 0);
                    acc[par][nt] = __builtin_amdgcn_mfma_f32_16x16x32_bf16(al, bh, acc[par][nt], 0, 0, 0);
                    acc[par][nt] = __builtin_amdgcn_mfma_f32_16x16x32_bf16(ah, bl, acc[par][nt], 0, 0, 0);
                }
            }
        }
    }

#pragma unroll
    for (int r = 0; r < 4; ++r) {
        int pr = tileBase + kg * 4 + r;
        int b2 = pr / HW, rr = pr % HW, y2 = rr / WW_, x2 = rr % WW_;
#pragma unroll
        for (int par = 0; par < 4; ++par) {
            int py = par >> 1, px = par & 1;
            size_t po = ((size_t)b2 * H2 + 2 * y2 + py) * W2 + 2 * x2 + px;
#pragma unroll
            for (int nt = 0; nt < 4; ++nt) {
                int co = nt * 16 + (lane & 15);
                float vv = acc[par][nt][r] + bias[co];
                size_t oo = po * 64 + co;
                ushort h = f2bf(vv);
                Ohi[oo] = h;
                Olo[oo] = f2bf(vv - bf2f(h));
            }
        }
    }
}

// ---------------------------------------------------------------- flow ------
__global__ __launch_bounds__(256) void flow_kernel(const ushort* __restrict__ dechi,
                                                   const ushort* __restrict__ declo,
                                                   const float* __restrict__ wf,
                                                   const float* __restrict__ bf2v,
                                                   float* __restrict__ flow) {
    __shared__ float wsm[1152];
    for (int i = threadIdx.x; i < 1152; i += 256) wsm[i] = wf[i];
    __syncthreads();
    int p = blockIdx.x * 256 + threadIdx.x;
    if (p >= 4 * OHW) return;
    int b = p / OHW, rem = p % OHW, oy = rem / W2, ox = rem % W2;
    float a0 = bf2v[0], a1 = bf2v[1];
    for (int ky = 0; ky < 3; ++ky) {
        int yy = oy + ky - 1;
        if ((unsigned)yy >= (unsigned)H2) continue;
        for (int kx = 0; kx < 3; ++kx) {
            int xx = ox + kx - 1;
            if ((unsigned)xx >= (unsigned)W2) continue;
            size_t base = ((size_t)b * OHW + yy * W2 + xx) * 64;
            int tap = ky * 3 + kx;
            for (int c4 = 0; c4 < 16; ++c4) {
                unsigned long long h8 = *(const unsigned long long*)(dechi + base + c4 * 4);
                unsigned long long l8 = *(const unsigned long long*)(declo + base + c4 * 4);
                for (int j = 0; j < 4; ++j) {
                    float f = bf2f((ushort)(h8 >> (16 * j))) + bf2f((ushort)(l8 >> (16 * j)));
                    int ci = c4 * 4 + j;
                    a0 += f * wsm[ci * 9 + tap];
                    a1 += f * wsm[(64 + ci) * 9 + tap];
                }
            }
        }
    }
    flow[(size_t)(b * 2 + 0) * OHW + rem] = a0;
    flow[(size_t)(b * 2 + 1) * OHW + rem] = a1;
}

// --------------------------------------------------------------- resize -----
__global__ void resize_kernel(const float* __restrict__ flow, float* __restrict__ out) {
    int idx = blockIdx.x * blockDim.x + threadIdx.x;
    int total = 4 * 2 * HO * WO;
    if (idx >= total) return;
    int ox = idx % WO;
    int oy = (idx / WO) % HO;
    int c = (idx / (WO * HO)) % 2;
    int b = idx / (WO * HO * 2);
    float sy = (oy + 0.5f) * 0.25f - 0.5f;
    float sx = (ox + 0.5f) * 0.25f - 0.5f;
    int y0 = (int)floorf(sy);
    int x0 = (int)floorf(sx);
    float fy = sy - y0;
    float fx = sx - x0;
    int y0c = min(max(y0, 0), H2 - 1);
    int y1c = min(max(y0 + 1, 0), H2 - 1);
    int x0c = min(max(x0, 0), W2 - 1);
    int x1c = min(max(x0 + 1, 0), W2 - 1);
    const float* fb = flow + (size_t)(b * 2 + c) * OHW;
    float v00 = fb[y0c * W2 + x0c];
    float v01 = fb[y0c * W2 + x1c];
    float v10 = fb[y1c * W2 + x0c];
    float v11 = fb[y1c * W2 + x1c];
    float v = (1.f - fy) * ((1.f - fx) * v00 + fx * v01)
            + fy * ((1.f - fx) * v10 + fx * v11);
    out[idx] = v * 4.0f;
}

// =================================================================== host ===
extern "C" void kernel_launch(void* const* d_in, const int* in_sizes, int n_in,
                              void* d_out, int out_size, void* d_ws, size_t ws_size,
                              hipStream_t stream) {
    const float* x1   = (const float*)d_in[0];
    const float* x2   = (const float*)d_in[1];
    const float* xt   = (const float*)d_in[2];
    const float* gln  = (const float*)d_in[3];
    const float* bln  = (const float*)d_in[4];
    const float* w0   = (const float*)d_in[5];
    const float* b0   = (const float*)d_in[6];
    const float* wr1  = (const float*)d_in[7];
    const float* br1  = (const float*)d_in[8];
    const float* wr2  = (const float*)d_in[9];
    const float* br2  = (const float*)d_in[10];
    const float* w2   = (const float*)d_in[11];
    const float* b2   = (const float*)d_in[12];
    const float* w3   = (const float*)d_in[13];
    const float* b3   = (const float*)d_in[14];
    const float* wdec = (const float*)d_in[15];
    const float* bdec = (const float*)d_in[16];
    const float* wf   = (const float*)d_in[17];
    const float* bfv  = (const float*)d_in[18];
    float* out = (float*)d_out;

    char* ws = (char*)d_ws;
    ushort* x1c   = (ushort*)(ws + 1048576);
    ushort* x2c   = (ushort*)(ws + 1048576 + 31457280);
    ushort* X0hi  = (ushort*)(ws + 67108864);
    ushort* X0lo  = (ushort*)(ws + 106430464);
    const size_t P = 7864320;
    ushort* y0hi = (ushort*)(ws + 1048576 + 0 * P);
    ushort* y0lo = (ushort*)(ws + 1048576 + 1 * P);
    ushort* t1hi = (ushort*)(ws + 1048576 + 2 * P);
    ushort* t1lo = (ushort*)(ws + 1048576 + 3 * P);
    ushort* t2hi = (ushort*)(ws + 1048576 + 4 * P);
    ushort* t2lo = (ushort*)(ws + 1048576 + 5 * P);
    ushort* dechi = (ushort*)(ws + 67108864);
    ushort* declo = (ushort*)(ws + 98566144);
    float*  flowb = (float*)(ws + 130023424);
    char* wp = ws + 146800640;
    ushort* W0hi  = (ushort*)(wp);             ushort* W0lo  = (ushort*)(wp + 368640);
    ushort* WR1hi = (ushort*)(wp + 737280);    ushort* WR1lo = (ushort*)(wp + 737280 + 73728);
    ushort* WR2hi = (ushort*)(wp + 884736);    ushort* WR2lo = (ushort*)(wp + 884736 + 73728);
    ushort* W2hi  = (ushort*)(wp + 1032192);   ushort* W2lo  = (ushort*)(wp + 1032192 + 73728);
    ushort* W3hi  = (ushort*)(wp + 1179648);   ushort* W3lo  = (ushort*)(wp + 1179648 + 73728);
    ushort* WDhi  = (ushort*)(wp + 1327104);   ushort* WDlo  = (ushort*)(wp + 1327104 + 73728);

    TapList T9; T9.n = 9;
    for (int ky = 0; ky < 3; ++ky)
        for (int kx = 0; kx < 3; ++kx) {
            int i = ky * 3 + kx;
            T9.dy[i] = ky - 1; T9.dx[i] = kx - 1; T9.slot[i] = i;
        }

    pack_w_kernel<<<90, 256, 0, stream>>>(w0, 305, 10, 0, W0hi, W0lo);
    pack_w_kernel<<<18, 256, 0, stream>>>(wr1, 64, 2, 0, WR1hi, WR1lo);
    pack_w_kernel<<<18, 256, 0, stream>>>(wr2, 64, 2, 0, WR2hi, WR2lo);
    pack_w_kernel<<<18, 256, 0, stream>>>(w2, 64, 2, 0, W2hi, W2lo);
    pack_w_kernel<<<18, 256, 0, stream>>>(w3, 64, 2, 0, W3hi, W3lo);
    pack_w_kernel<<<18, 256, 0, stream>>>(wdec, 64, 2, 1, WDhi, WDlo);

    // fused stats + normalize + pack (x1, x2, xt) + corr-channel zero-fill
    normpack_kernel<<<dim3(480, 3, 4), 256, 0, stream>>>(
        x1, x2, xt, gln, bln, x1c, x2c, X0hi, X0lo);
    // correlation via MFMA band-matmul
    corr_mfma_kernel<<<960, 256, 0, stream>>>(x1c, x2c, X0hi, X0lo);

    conv_mfma_kernel<<<480, 256, 0, stream>>>(X0hi, X0lo, C0, 10, W0hi, W0lo, b0, T9,
        y0hi, y0lo, nullptr, nullptr, 0.f, 0, 0);
    conv_mfma_kernel<<<480, 256, 0, stream>>>(y0hi, y0lo, 64, 2, WR1hi, WR1lo, br1, T9,
        t1hi, t1lo, nullptr, nullptr, 0.1f, 1, 0);
    conv_mfma_kernel<<<480, 256, 0, stream>>>(t1hi, t1lo, 64, 2, WR2hi, WR2lo, br2, T9,
        t2hi, t2lo, y0hi, y0lo, 0.1f, 1, 1);
    conv_mfma_kernel<<<480, 256, 0, stream>>>(t2hi, t2lo, 64, 2, W2hi, W2lo, b2, T9,
        t1hi, t1lo, nullptr, nullptr, 0.2f, 1, 0);
    conv_mfma_kernel<<<480, 256, 0, stream>>>(t1hi, t1lo, 64, 2, W3hi, W3lo, b3, T9,
        t2hi, t2lo, nullptr, nullptr, 0.2f, 1, 0);
    deconv_fused_kernel<<<960, 256, 0, stream>>>(t2hi, t2lo, WDhi, WDlo, bdec, dechi, declo);

    flow_kernel<<<960, 256, 0, stream>>>(dechi, declo, wf, bfv, flowb);
    resize_kernel<<<30720, 256, 0, stream>>>(flowb, out);

    (void)in_sizes; (void)n_in; (void)out_size; (void)ws_size;
}

// Round 5
// 606.903 us; speedup vs baseline: 1.5647x; 1.0426x over previous
//
#include <hip/hip_runtime.h>
#include <math.h>

#define HH_ 96
#define WW_ 160
#define HW 15360          // 96*160
#define NPIX 61440        // 4*HW
#define CC 256
#define C0 320            // padded conv0 Cin
#define FF 64
#define H2 192
#define W2 320
#define OHW 61440         // 192*320
#define HO 768
#define WO 1280

typedef __attribute__((ext_vector_type(8))) short short8;
typedef __attribute__((ext_vector_type(4))) float f32x4;

__device__ __forceinline__ float bf2f(ushort u) {
    union { unsigned int i; float f; } v; v.i = ((unsigned int)u) << 16; return v.f;
}
__device__ __forceinline__ ushort f2bf(float f) {
    union { float f; unsigned int i; } v; v.f = f;
    unsigned int u = v.i;
    return (ushort)((u + 0x7FFFu + ((u >> 16) & 1u)) >> 16);
}

// ---------------- fused stats + normalize/LN + NHWC bf16 pack ---------------
__global__ __launch_bounds__(256) void normpack_kernel(
    const float* __restrict__ x1, const float* __restrict__ x2, const float* __restrict__ xt,
    const float* __restrict__ gam, const float* __restrict__ bet,
    ushort* __restrict__ x1c, ushort* __restrict__ x2c,
    ushort* __restrict__ Xhi, ushort* __restrict__ Xlo) {
    __shared__ float tile[32 * 257];
    const int t = threadIdx.x;
    const int pxt = blockIdx.x, which = blockIdx.y, b = blockIdx.z;
    const float* src = (which == 0 ? x1 : which == 1 ? x2 : xt);
    src += (size_t)b * CC * HW + pxt * 32;

    {
        int px_l = t & 31, c_hi = t >> 5;
#pragma unroll 8
        for (int i = 0; i < 32; ++i) {
            int c = i * 8 + c_hi;
            tile[px_l * 257 + c] = src[(size_t)c * HW + px_l];
        }
    }
    __syncthreads();

    const int px = t >> 3, oct = t & 7;
    float s1 = 0.f, s2 = 0.f;
    {
        const float* row = &tile[px * 257];
#pragma unroll
        for (int i = 0; i < 32; ++i) {
            int cc = oct * 32 + ((i + oct * 4) & 31);
            float v = row[cc];
            s1 += v; s2 += v * v;
        }
    }
    s1 += __shfl_xor(s1, 1); s1 += __shfl_xor(s1, 2); s1 += __shfl_xor(s1, 4);
    s2 += __shfl_xor(s2, 1); s2 += __shfl_xor(s2, 2); s2 += __shfl_xor(s2, 4);

    const int p = b * HW + pxt * 32 + px;
    const float* row = &tile[px * 257];
    if (which < 2) {
        float inv = 1.f / fmaxf(sqrtf(s2), 1e-12f);
        ushort* dst = (which == 0 ? x1c : x2c);
        size_t ob = (size_t)p * CC + oct * 32;
#pragma unroll
        for (int g = 0; g < 4; ++g) {
            short8 v;
#pragma unroll
            for (int j = 0; j < 8; ++j)
                v[j] = (short)f2bf(row[oct * 32 + g * 8 + j] * inv);
            *(short8*)(dst + ob + g * 8) = v;
        }
    } else {
        float m = s1 * (1.f / 256.f);
        float var = fmaxf(s2 * (1.f / 256.f) - m * m, 0.f);
        float rs = rsqrtf(var + 1e-5f);
        size_t ob = (size_t)p * C0 + oct * 32;
#pragma unroll
        for (int g = 0; g < 4; ++g) {
            short8 vh, vl;
#pragma unroll
            for (int j = 0; j < 8; ++j) {
                int c = oct * 32 + g * 8 + j;
                float f = (row[c] - m) * rs * gam[c] + bet[c];
                ushort h = f2bf(f);
                vh[j] = (short)h;
                vl[j] = (short)f2bf(f - bf2f(h));
            }
            *(short8*)(Xhi + ob + g * 8) = vh;
            *(short8*)(Xlo + ob + g * 8) = vl;
        }
        short8 z = {0, 0, 0, 0, 0, 0, 0, 0};
        size_t zb = (size_t)p * C0 + 256 + oct * 8;
        *(short8*)(Xhi + zb) = z;
        *(short8*)(Xlo + zb) = z;
    }
}

// ---------------------------------------------------------------- corr ------
// XCD-chunked blocks: block -> (b, u-quad, xt); wave u = uq*4+wv.
__global__ __launch_bounds__(256) void corr_mfma_kernel(
    const ushort* __restrict__ x1c, const ushort* __restrict__ x2c,
    ushort* __restrict__ Xhi, ushort* __restrict__ Xlo) {
    const int lane = threadIdx.x & 63;
    const int wv = threadIdx.x >> 6;
    const int sid = ((blockIdx.x & 7) * 120) + (blockIdx.x >> 3);   // 960 blocks
    const int b  = sid / 240;
    const int rem = sid % 240;
    const int uq = rem / 10, xt = rem % 10;
    const int u = uq * 4 + wv;
    const int x0 = xt * 16;
    const int jl = lane & 15;
    const int kg = lane >> 4;
    const short8 zero8 = {0, 0, 0, 0, 0, 0, 0, 0};

    short8 qf[8];
    {
        size_t qb = ((size_t)b * HW + u * WW_ + x0 + jl) * CC + kg * 8;
#pragma unroll
        for (int ks = 0; ks < 8; ++ks)
            qf[ks] = *(const short8*)(x1c + qb + ks * 32);
    }

    for (int dy = -3; dy <= 3; ++dy) {
        const int y = u + dy;
        if ((unsigned)y >= (unsigned)HH_) continue;
        const int w = u + 2 * dy;
        const bool rowok = (unsigned)w < (unsigned)HH_;

        f32x4 acc0 = (f32x4){0.f, 0.f, 0.f, 0.f};
        f32x4 acc1 = (f32x4){0.f, 0.f, 0.f, 0.f};
        if (rowok) {
#pragma unroll
            for (int nt = 0; nt < 2; ++nt) {
                int kx = x0 - 6 + jl + 16 * nt;
                bool ok = (unsigned)kx < (unsigned)WW_;
                int kxc = min(max(kx, 0), WW_ - 1);
                size_t kb = ((size_t)b * HW + w * WW_ + kxc) * CC + kg * 8;
#pragma unroll
                for (int ks = 0; ks < 8; ++ks) {
                    short8 bv = *(const short8*)(x2c + kb + ks * 32);
                    if (!ok) bv = zero8;
                    if (nt == 0)
                        acc0 = __builtin_amdgcn_mfma_f32_16x16x32_bf16(qf[ks], bv, acc0, 0, 0, 0);
                    else
                        acc1 = __builtin_amdgcn_mfma_f32_16x16x32_bf16(qf[ks], bv, acc1, 0, 0, 0);
                }
            }
        }
#pragma unroll
        for (int nt = 0; nt < 2; ++nt) {
            int j = jl + 16 * nt;
#pragma unroll
            for (int r = 0; r < 4; ++r) {
                int q = kg * 4 + r;
                int tt = j - q - 6;
                if (tt & 1) continue;
                int dx = tt >> 1;
                if (dx < -3 || dx > 3) continue;
                int cx = x0 + q + dx;
                if ((unsigned)cx >= (unsigned)WW_) continue;
                float v = rowok ? (nt == 0 ? acc0[r] : acc1[r]) : 0.f;
                size_t o = ((size_t)(b * HW + y * WW_ + cx)) * C0
                         + 256 + (dy + 3) * 7 + (dx + 3);
                ushort h = f2bf(v);
                Xhi[o] = h;
                Xlo[o] = f2bf(v - bf2f(h));
            }
        }
    }
}

// ------------------------------------------------------------ weight pack ---
__global__ void pack_w_kernel(const float* __restrict__ w, int CinReal, int KC, int isDeconv,
                              ushort* __restrict__ whi, ushort* __restrict__ wlo) {
    int gid = blockIdx.x * blockDim.x + threadIdx.x;
    int total = 9 * KC * 4 * 64;
    if (gid >= total) return;
    int lane = gid & 63;
    int nt = (gid >> 6) & 3;
    int kc = (gid >> 8) % KC;
    int slot = (gid >> 8) / KC;
    int co = nt * 16 + (lane & 15);
    int ky = slot / 3, kx = slot % 3;
    for (int j = 0; j < 8; ++j) {
        int ci = kc * 32 + (lane >> 4) * 8 + j;
        float v = 0.f;
        if (ci < CinReal) {
            if (isDeconv) v = w[((size_t)(ci * 64 + co) * 3 + (2 - ky)) * 3 + (2 - kx)];
            else          v = w[((size_t)(co * CinReal + ci) * 3 + ky) * 3 + kx];
        }
        ushort h = f2bf(v);
        whi[(size_t)gid * 8 + j] = h;
        wlo[(size_t)gid * 8 + j] = f2bf(v - bf2f(h));
    }
}

// -------------------------------------------------------- MFMA conv core ----
// XCD-chunked blocks: block -> (b, y-quad, x-window 32); wave y = yq*4+wv.
struct TapList { int dy[9]; int dx[9]; int slot[9]; int n; };

__global__ __launch_bounds__(256) void conv_mfma_kernel(
    const ushort* __restrict__ Ahi, const ushort* __restrict__ Alo,
    int CIN, int KC,
    const ushort* __restrict__ Whi, const ushort* __restrict__ Wlo,
    const float* __restrict__ bias,
    TapList taps,
    ushort* __restrict__ Ohi, ushort* __restrict__ Olo,
    const ushort* __restrict__ Rhi, const ushort* __restrict__ Rlo,
    float slope, int act, int hasres) {
    const int lane = threadIdx.x & 63;
    const int wave = threadIdx.x >> 6;
    const int kg = lane >> 4;
    const short8 zero8 = {0, 0, 0, 0, 0, 0, 0, 0};

    const int sid = ((blockIdx.x & 7) * 60) + (blockIdx.x >> 3);   // 480 blocks
    const int b0 = sid / 120;
    const int rm = sid % 120;
    const int yq = rm / 5, xw = rm % 5;
    const int y0 = yq * 4 + wave;
    const int x0 = xw * 32;
    const int pmx = x0 + (lane & 15);
    const size_t rowbase = (size_t)b0 * HW;

    f32x4 acc[2][4];
    for (int s = 0; s < 2; ++s)
        for (int nt = 0; nt < 4; ++nt)
            acc[s][nt] = (f32x4){0.f, 0.f, 0.f, 0.f};

    for (int t = 0; t < taps.n; ++t) {
        int dy = taps.dy[t], dx = taps.dx[t];
        int yy = y0 + dy;
        bool rowok = (unsigned)yy < 96u;
        int yyc = min(max(yy, 0), 95);
        int xx0 = pmx + dx, xx1 = pmx + 16 + dx;
        bool v0 = rowok && (unsigned)xx0 < 160u;
        bool v1 = rowok && (unsigned)xx1 < 160u;
        int xx0c = min(max(xx0, 0), 159), xx1c = min(max(xx1, 0), 159);
        size_t a0 = (rowbase + yyc * WW_ + xx0c) * (size_t)CIN + kg * 8;
        size_t a1 = (rowbase + yyc * WW_ + xx1c) * (size_t)CIN + kg * 8;
        const ushort* wh_t = Whi + (size_t)taps.slot[t] * KC * 2048;
        const ushort* wl_t = Wlo + (size_t)taps.slot[t] * KC * 2048;
        for (int kc = 0; kc < KC; ++kc) {
            short8 ah0 = *(const short8*)(Ahi + a0 + kc * 32);
            short8 al0 = *(const short8*)(Alo + a0 + kc * 32);
            short8 ah1 = *(const short8*)(Ahi + a1 + kc * 32);
            short8 al1 = *(const short8*)(Alo + a1 + kc * 32);
            if (!v0) { ah0 = zero8; al0 = zero8; }
            if (!v1) { ah1 = zero8; al1 = zero8; }
#pragma unroll
            for (int nt = 0; nt < 4; ++nt) {
                size_t wo = (((size_t)kc * 4 + nt) * 64 + lane) * 8;
                short8 bh = *(const short8*)(wh_t + wo);
                short8 bl = *(const short8*)(wl_t + wo);
                acc[0][nt] = __builtin_amdgcn_mfma_f32_16x16x32_bf16(ah0, bh, acc[0][nt], 0, 0, 0);
                acc[1][nt] = __builtin_amdgcn_mfma_f32_16x16x32_bf16(ah1, bh, acc[1][nt], 0, 0, 0);
                acc[0][nt] = __builtin_amdgcn_mfma_f32_16x16x32_bf16(al0, bh, acc[0][nt], 0, 0, 0);
                acc[1][nt] = __builtin_amdgcn_mfma_f32_16x16x32_bf16(al1, bh, acc[1][nt], 0, 0, 0);
                acc[0][nt] = __builtin_amdgcn_mfma_f32_16x16x32_bf16(ah0, bl, acc[0][nt], 0, 0, 0);
                acc[1][nt] = __builtin_amdgcn_mfma_f32_16x16x32_bf16(ah1, bl, acc[1][nt], 0, 0, 0);
            }
        }
    }

    for (int s = 0; s < 2; ++s) {
        for (int r = 0; r < 4; ++r) {
            size_t pr = rowbase + y0 * WW_ + x0 + s * 16 + kg * 4 + r;
            for (int nt = 0; nt < 4; ++nt) {
                int co = nt * 16 + (lane & 15);
                float vv = acc[s][nt][r] + bias[co];
                size_t oo = pr * 64 + co;
                if (hasres) vv += bf2f(Rhi[oo]) + bf2f(Rlo[oo]);
                if (act) vv = vv >= 0.f ? vv : vv * slope;
                ushort h = f2bf(vv);
                Ohi[oo] = h;
                Olo[oo] = f2bf(vv - bf2f(h));
            }
        }
    }
}

// ------------------------------------------- fused transposed conv (4 par) --
__global__ __launch_bounds__(256) void deconv_fused_kernel(
    const ushort* __restrict__ Ahi, const ushort* __restrict__ Alo,
    const ushort* __restrict__ Whi, const ushort* __restrict__ Wlo,
    const float* __restrict__ bias,
    ushort* __restrict__ Ohi, ushort* __restrict__ Olo) {
    const int lane = threadIdx.x & 63;
    const int wave = threadIdx.x >> 6;
    const int kg = lane >> 4;
    const short8 zero8 = {0, 0, 0, 0, 0, 0, 0, 0};

    const int sid = ((blockIdx.x & 7) * 120) + (blockIdx.x >> 3);   // 960 blocks
    const int b0 = sid / 240;
    const int rm = sid % 240;
    const int yq = rm / 10, xh = rm % 10;
    const int y0 = yq * 4 + wave;
    const int x0 = xh * 16;
    const size_t rowbase = (size_t)b0 * HW;

    f32x4 acc[4][4];   // [parity][nt]
#pragma unroll
    for (int p = 0; p < 4; ++p)
#pragma unroll
        for (int nt = 0; nt < 4; ++nt) acc[p][nt] = (f32x4){0.f, 0.f, 0.f, 0.f};

    const int nuse[4]   = {4, 2, 2, 1};
    const int upar[4][4] = {{0, 1, 2, 3}, {1, 3, -1, -1}, {2, 3, -1, -1}, {3, -1, -1, -1}};
    const int uslt[4][4] = {{4, 3, 1, 0}, {5, 2, -1, -1}, {7, 6, -1, -1}, {8, -1, -1, -1}};

#pragma unroll
    for (int o = 0; o < 4; ++o) {
        const int ody = o >> 1, odx = o & 1;
        int yy = y0 + ody, xx = x0 + (lane & 15) + odx;
        bool v = (unsigned)yy < 96u && (unsigned)xx < 160u;
        int yyc = min(yy, 95), xxc = min(xx, 159);
        size_t a = (rowbase + yyc * WW_ + xxc) * 64 + kg * 8;
        for (int kc = 0; kc < 2; ++kc) {
            short8 ah = *(const short8*)(Ahi + a + kc * 32);
            short8 al = *(const short8*)(Alo + a + kc * 32);
            if (!v) { ah = zero8; al = zero8; }
#pragma unroll
            for (int u = 0; u < 4; ++u) {
                if (u >= nuse[o]) break;
                int par = upar[o][u], slot = uslt[o][u];
#pragma unroll
                for (int nt = 0; nt < 4; ++nt) {
                    size_t wo = ((size_t)slot * 2 + kc) * 2048 + ((size_t)nt * 64 + lane) * 8;
                    short8 bh = *(const short8*)(Whi + wo);
                    short8 bl = *(const short8*)(Wlo + wo);
                    acc[par][nt] = __builtin_amdgcn_mfma_f32_16x16x32_bf16(ah, bh, acc[par][nt], 0, 0, 0);
                    acc[par][nt] = __builtin_amdgcn_mfma_f32_16x16x32_bf16(al, bh, acc[par][nt], 0, 0, 0);
                    acc[par][nt] = __builtin_amdgcn_mfma_f32_16x16x32_bf16(ah, bl, acc[par][nt], 0, 0, 0);
                }
            }
        }
    }

#pragma unroll
    for (int r = 0; r < 4; ++r) {
        int x2 = x0 + kg * 4 + r;
#pragma unroll
        for (int par = 0; par < 4; ++par) {
            int py = par >> 1, px = par & 1;
            size_t po = ((size_t)b0 * H2 + 2 * y0 + py) * W2 + 2 * x2 + px;
#pragma unroll
            for (int nt = 0; nt < 4; ++nt) {
                int co = nt * 16 + (lane & 15);
                float vv = acc[par][nt][r] + bias[co];
                size_t oo = po * 64 + co;
                ushort h = f2bf(vv);
                Ohi[oo] = h;
                Olo[oo] = f2bf(vv - bf2f(h));
            }
        }
    }
}

// ---------------------------------------------------------------- flow ------
__global__ __launch_bounds__(256) void flow_kernel(const ushort* __restrict__ dechi,
                                                   const ushort* __restrict__ declo,
                                                   const float* __restrict__ wf,
                                                   const float* __restrict__ bf2v,
                                                   float* __restrict__ flow) {
    __shared__ float wsm[1152];
    for (int i = threadIdx.x; i < 1152; i += 256) wsm[i] = wf[i];
    __syncthreads();
    int fid = ((blockIdx.x & 7) * 120) + (blockIdx.x >> 3);   // 960 blocks
    int p = fid * 256 + threadIdx.x;
    if (p >= 4 * OHW) return;
    int b = p / OHW, rem = p % OHW, oy = rem / W2, ox = rem % W2;
    float a0 = bf2v[0], a1 = bf2v[1];
    for (int ky = 0; ky < 3; ++ky) {
        int yy = oy + ky - 1;
        if ((unsigned)yy >= (unsigned)H2) continue;
        for (int kx = 0; kx < 3; ++kx) {
            int xx = ox + kx - 1;
            if ((unsigned)xx >= (unsigned)W2) continue;
            size_t base = ((size_t)b * OHW + yy * W2 + xx) * 64;
            int tap = ky * 3 + kx;
            for (int c4 = 0; c4 < 16; ++c4) {
                unsigned long long h8 = *(const unsigned long long*)(dechi + base + c4 * 4);
                unsigned long long l8 = *(const unsigned long long*)(declo + base + c4 * 4);
                for (int j = 0; j < 4; ++j) {
                    float f = bf2f((ushort)(h8 >> (16 * j))) + bf2f((ushort)(l8 >> (16 * j)));
                    int ci = c4 * 4 + j;
                    a0 += f * wsm[ci * 9 + tap];
                    a1 += f * wsm[(64 + ci) * 9 + tap];
                }
            }
        }
    }
    flow[(size_t)(b * 2 + 0) * OHW + rem] = a0;
    flow[(size_t)(b * 2 + 1) * OHW + rem] = a1;
}

// --------------------------------------------------------------- resize -----
__global__ void resize_kernel(const float* __restrict__ flow, float* __restrict__ out) {
    int idx = blockIdx.x * blockDim.x + threadIdx.x;
    int total = 4 * 2 * HO * WO;
    if (idx >= total) return;
    int ox = idx % WO;
    int oy = (idx / WO) % HO;
    int c = (idx / (WO * HO)) % 2;
    int b = idx / (WO * HO * 2);
    float sy = (oy + 0.5f) * 0.25f - 0.5f;
    float sx = (ox + 0.5f) * 0.25f - 0.5f;
    int y0 = (int)floorf(sy);
    int x0 = (int)floorf(sx);
    float fy = sy - y0;
    float fx = sx - x0;
    int y0c = min(max(y0, 0), H2 - 1);
    int y1c = min(max(y0 + 1, 0), H2 - 1);
    int x0c = min(max(x0, 0), W2 - 1);
    int x1c = min(max(x0 + 1, 0), W2 - 1);
    const float* fb = flow + (size_t)(b * 2 + c) * OHW;
    float v00 = fb[y0c * W2 + x0c];
    float v01 = fb[y0c * W2 + x1c];
    float v10 = fb[y1c * W2 + x0c];
    float v11 = fb[y1c * W2 + x1c];
    float v = (1.f - fy) * ((1.f - fx) * v00 + fx * v01)
            + fy * ((1.f - fx) * v10 + fx * v11);
    out[idx] = v * 4.0f;
}

// =================================================================== host ===
extern "C" void kernel_launch(void* const* d_in, const int* in_sizes, int n_in,
                              void* d_out, int out_size, void* d_ws, size_t ws_size,
                              hipStream_t stream) {
    const float* x1   = (const float*)d_in[0];
    const float* x2   = (const float*)d_in[1];
    const float* xt   = (const float*)d_in[2];
    const float* gln  = (const float*)d_in[3];
    const float* bln  = (const float*)d_in[4];
    const float* w0   = (const float*)d_in[5];
    const float* b0   = (const float*)d_in[6];
    const float* wr1  = (const float*)d_in[7];
    const float* br1  = (const float*)d_in[8];
    const float* wr2  = (const float*)d_in[9];
    const float* br2  = (const float*)d_in[10];
    const float* w2   = (const float*)d_in[11];
    const float* b2   = (const float*)d_in[12];
    const float* w3   = (const float*)d_in[13];
    const float* b3   = (const float*)d_in[14];
    const float* wdec = (const float*)d_in[15];
    const float* bdec = (const float*)d_in[16];
    const float* wf   = (const float*)d_in[17];
    const float* bfv  = (const float*)d_in[18];
    float* out = (float*)d_out;

    char* ws = (char*)d_ws;
    ushort* x1c   = (ushort*)(ws + 1048576);
    ushort* x2c   = (ushort*)(ws + 1048576 + 31457280);
    ushort* X0hi  = (ushort*)(ws + 67108864);
    ushort* X0lo  = (ushort*)(ws + 106430464);
    const size_t P = 7864320;
    ushort* y0hi = (ushort*)(ws + 1048576 + 0 * P);
    ushort* y0lo = (ushort*)(ws + 1048576 + 1 * P);
    ushort* t1hi = (ushort*)(ws + 1048576 + 2 * P);
    ushort* t1lo = (ushort*)(ws + 1048576 + 3 * P);
    ushort* t2hi = (ushort*)(ws + 1048576 + 4 * P);
    ushort* t2lo = (ushort*)(ws + 1048576 + 5 * P);
    ushort* dechi = (ushort*)(ws + 67108864);
    ushort* declo = (ushort*)(ws + 98566144);
    float*  flowb = (float*)(ws + 130023424);
    char* wp = ws + 146800640;
    ushort* W0hi  = (ushort*)(wp);             ushort* W0lo  = (ushort*)(wp + 368640);
    ushort* WR1hi = (ushort*)(wp + 737280);    ushort* WR1lo = (ushort*)(wp + 737280 + 73728);
    ushort* WR2hi = (ushort*)(wp + 884736);    ushort* WR2lo = (ushort*)(wp + 884736 + 73728);
    ushort* W2hi  = (ushort*)(wp + 1032192);   ushort* W2lo  = (ushort*)(wp + 1032192 + 73728);
    ushort* W3hi  = (ushort*)(wp + 1179648);   ushort* W3lo  = (ushort*)(wp + 1179648 + 73728);
    ushort* WDhi  = (ushort*)(wp + 1327104);   ushort* WDlo  = (ushort*)(wp + 1327104 + 73728);

    TapList T9; T9.n = 9;
    for (int ky = 0; ky < 3; ++ky)
        for (int kx = 0; kx < 3; ++kx) {
            int i = ky * 3 + kx;
            T9.dy[i] = ky - 1; T9.dx[i] = kx - 1; T9.slot[i] = i;
        }

    pack_w_kernel<<<90, 256, 0, stream>>>(w0, 305, 10, 0, W0hi, W0lo);
    pack_w_kernel<<<18, 256, 0, stream>>>(wr1, 64, 2, 0, WR1hi, WR1lo);
    pack_w_kernel<<<18, 256, 0, stream>>>(wr2, 64, 2, 0, WR2hi, WR2lo);
    pack_w_kernel<<<18, 256, 0, stream>>>(w2, 64, 2, 0, W2hi, W2lo);
    pack_w_kernel<<<18, 256, 0, stream>>>(w3, 64, 2, 0, W3hi, W3lo);
    pack_w_kernel<<<18, 256, 0, stream>>>(wdec, 64, 2, 1, WDhi, WDlo);

    normpack_kernel<<<dim3(480, 3, 4), 256, 0, stream>>>(
        x1, x2, xt, gln, bln, x1c, x2c, X0hi, X0lo);
    corr_mfma_kernel<<<960, 256, 0, stream>>>(x1c, x2c, X0hi, X0lo);

    conv_mfma_kernel<<<480, 256, 0, stream>>>(X0hi, X0lo, C0, 10, W0hi, W0lo, b0, T9,
        y0hi, y0lo, nullptr, nullptr, 0.f, 0, 0);
    conv_mfma_kernel<<<480, 256, 0, stream>>>(y0hi, y0lo, 64, 2, WR1hi, WR1lo, br1, T9,
        t1hi, t1lo, nullptr, nullptr, 0.1f, 1, 0);
    conv_mfma_kernel<<<480, 256, 0, stream>>>(t1hi, t1lo, 64, 2, WR2hi, WR2lo, br2, T9,
        t2hi, t2lo, y0hi, y0lo, 0.1f, 1, 1);
    conv_mfma_kernel<<<480, 256, 0, stream>>>(t2hi, t2lo, 64, 2, W2hi, W2lo, b2, T9,
        t1hi, t1lo, nullptr, nullptr, 0.2f, 1, 0);
    conv_mfma_kernel<<<480, 256, 0, stream>>>(t1hi, t1lo, 64, 2, W3hi, W3lo, b3, T9,
        t2hi, t2lo, nullptr, nullptr, 0.2f, 1, 0);
    deconv_fused_kernel<<<960, 256, 0, stream>>>(t2hi, t2lo, WDhi, WDlo, bdec, dechi, declo);

    flow_kernel<<<960, 256, 0, stream>>>(dechi, declo, wf, bfv, flowb);
    resize_kernel<<<30720, 256, 0, stream>>>(flowb, out);

    (void)in_sizes; (void)n_in; (void)out_size; (void)ws_size;
}